// Round 1
// baseline (270.021 us; speedup 1.0000x reference)
//
#include <hip/hip_runtime.h>

#define D 128
#define E_EDGES 50000
#define S_NEG 16
#define N_A 100000
#define N_B 50000
#define ES (E_EDGES * S_NEG)

// ---------------------------------------------------------------------------
// ws layout:
//   int   cntA[4 * N_A]   planes: 0=pos0, 1=nh0, 2=nh1, 3=nt0   (counts into emb_A)
//   int   cntB[2 * N_B]   planes: 0=pos1, 1=nt1                 (counts into emb_B)
//   float svec[6 * D]     weighted sums, job order: pos0,pos1,nh0,nh1,nt0,nt1
//   float cvec[6 * D]     c_j = scale_j * K_{j%2} @ s_j
//   float PA[N_A * 5]     PA[n*5+k] = emb_A[n] . c_k   (k = 0..4)
//   float PB[N_B]         PB[n]     = emb_B[n] . c_5
// ---------------------------------------------------------------------------

__global__ void k_count(const int* __restrict__ ei0, const int* __restrict__ ei1,
                        const int* __restrict__ nh0, const int* __restrict__ nh1,
                        const int* __restrict__ nt0, const int* __restrict__ nt1,
                        int* __restrict__ cntA, int* __restrict__ cntB) {
    const int total = 4 * E_EDGES + 2 * ES;  // 1.8M items
    for (int t = blockIdx.x * blockDim.x + threadIdx.x; t < total;
         t += gridDim.x * blockDim.x) {
        if (t < E_EDGES) {
            atomicAdd(&cntA[ei0[E_EDGES + t]], 1);                       // pos0 tails (A)
        } else if (t < 2 * E_EDGES) {
            atomicAdd(&cntB[ei1[E_EDGES + (t - E_EDGES)]], 1);           // pos1 tails (B)
        } else if (t < 3 * E_EDGES) {
            atomicAdd(&cntA[N_A + nh0[(t - 2 * E_EDGES) * S_NEG]], 1);   // nh0 col 0 (A)
        } else if (t < 4 * E_EDGES) {
            atomicAdd(&cntA[2 * N_A + nh1[(t - 3 * E_EDGES) * S_NEG]], 1); // nh1 col 0 (A)
        } else if (t < 4 * E_EDGES + ES) {
            atomicAdd(&cntA[3 * N_A + nt0[t - 4 * E_EDGES]], 1);         // nt0 flat (A)
        } else {
            atomicAdd(&cntB[N_B + nt1[t - 4 * E_EDGES - ES]], 1);        // nt1 flat (B)
        }
    }
}

// Weighted table scan: s_j = sum_n cnt_j[n] * emb[n].
// 32 lanes per row, float4 per lane; per-group accumulators -> LDS -> global atomics.
__global__ void k_scan1(const float* __restrict__ embA, const float* __restrict__ embB,
                        const int* __restrict__ cntA, const int* __restrict__ cntB,
                        float* __restrict__ svec, int blocksA) {
    __shared__ float sds[4 * D];
    const int tid = threadIdx.x;
    const int l = tid & 31;
    const int grp = tid >> 5;  // 0..7

    for (int j = tid; j < 4 * D; j += blockDim.x) sds[j] = 0.f;
    __syncthreads();

    if ((int)blockIdx.x < blocksA) {
        const int gStride = blocksA * 8;
        float a0=0,a1=0,a2=0,a3=0, b0=0,b1=0,b2=0,b3=0;
        float c0=0,c1=0,c2=0,c3=0, d0=0,d1=0,d2=0,d3=0;
        for (int n = blockIdx.x * 8 + grp; n < N_A; n += gStride) {
            const int w0 = cntA[n], w1 = cntA[N_A + n];
            const int w2 = cntA[2 * N_A + n], w3 = cntA[3 * N_A + n];
            if ((w0 | w1 | w2 | w3) == 0) continue;
            const float4 r = *reinterpret_cast<const float4*>(embA + (size_t)n * D + 4 * l);
            float f;
            f = (float)w0; a0 += f*r.x; a1 += f*r.y; a2 += f*r.z; a3 += f*r.w;
            f = (float)w1; b0 += f*r.x; b1 += f*r.y; b2 += f*r.z; b3 += f*r.w;
            f = (float)w2; c0 += f*r.x; c1 += f*r.y; c2 += f*r.z; c3 += f*r.w;
            f = (float)w3; d0 += f*r.x; d1 += f*r.y; d2 += f*r.z; d3 += f*r.w;
        }
        atomicAdd(&sds[0*D + 4*l+0], a0); atomicAdd(&sds[0*D + 4*l+1], a1);
        atomicAdd(&sds[0*D + 4*l+2], a2); atomicAdd(&sds[0*D + 4*l+3], a3);
        atomicAdd(&sds[1*D + 4*l+0], b0); atomicAdd(&sds[1*D + 4*l+1], b1);
        atomicAdd(&sds[1*D + 4*l+2], b2); atomicAdd(&sds[1*D + 4*l+3], b3);
        atomicAdd(&sds[2*D + 4*l+0], c0); atomicAdd(&sds[2*D + 4*l+1], c1);
        atomicAdd(&sds[2*D + 4*l+2], c2); atomicAdd(&sds[2*D + 4*l+3], c3);
        atomicAdd(&sds[3*D + 4*l+0], d0); atomicAdd(&sds[3*D + 4*l+1], d1);
        atomicAdd(&sds[3*D + 4*l+2], d2); atomicAdd(&sds[3*D + 4*l+3], d3);
        __syncthreads();
        // plane -> job: 0->0 (pos0), 1->2 (nh0), 2->3 (nh1), 3->4 (nt0)
        for (int j = tid; j < 4 * D; j += blockDim.x) {
            const int plane = j >> 7, i = j & (D - 1);
            const int job = (plane == 0) ? 0 : (plane + 1);
            atomicAdd(&svec[job * D + i], sds[j]);
        }
    } else {
        const int bBlocks = gridDim.x - blocksA;
        const int gStride = bBlocks * 8;
        float a0=0,a1=0,a2=0,a3=0, b0=0,b1=0,b2=0,b3=0;
        for (int n = (blockIdx.x - blocksA) * 8 + grp; n < N_B; n += gStride) {
            const int w0 = cntB[n], w1 = cntB[N_B + n];
            if ((w0 | w1) == 0) continue;
            const float4 r = *reinterpret_cast<const float4*>(embB + (size_t)n * D + 4 * l);
            float f;
            f = (float)w0; a0 += f*r.x; a1 += f*r.y; a2 += f*r.z; a3 += f*r.w;
            f = (float)w1; b0 += f*r.x; b1 += f*r.y; b2 += f*r.z; b3 += f*r.w;
        }
        atomicAdd(&sds[0*D + 4*l+0], a0); atomicAdd(&sds[0*D + 4*l+1], a1);
        atomicAdd(&sds[0*D + 4*l+2], a2); atomicAdd(&sds[0*D + 4*l+3], a3);
        atomicAdd(&sds[1*D + 4*l+0], b0); atomicAdd(&sds[1*D + 4*l+1], b1);
        atomicAdd(&sds[1*D + 4*l+2], b2); atomicAdd(&sds[1*D + 4*l+3], b3);
        __syncthreads();
        // plane -> job: 0->1 (pos1), 1->5 (nt1)
        for (int j = tid; j < 2 * D; j += blockDim.x) {
            const int plane = j >> 7, i = j & (D - 1);
            const int job = (plane == 0) ? 1 : 5;
            atomicAdd(&svec[job * D + i], sds[j]);
        }
    }
}

// c_j[i] = scale_j * sum_k K_{j%2}[i,k] * s_j[k];  scale = 16 for nh jobs (2,3).
__global__ void k_matvec(const float* __restrict__ rel, const float* __restrict__ svec,
                         float* __restrict__ cvec) {
    const int j = blockIdx.x;  // 0..5; even -> K0, odd -> K1
    const float* Kp = rel + (size_t)(j & 1) * D * D;
    const float scale = (j == 2 || j == 3) ? (float)S_NEG : 1.0f;
    __shared__ float sv[D];
    sv[threadIdx.x] = svec[j * D + threadIdx.x];
    __syncthreads();
    const int i = threadIdx.x;
    float acc = 0.f;
#pragma unroll 8
    for (int k = 0; k < D; ++k) acc += Kp[(size_t)i * D + k] * sv[k];
    cvec[j * D + i] = acc * scale;
}

// PA[n*5+k] = emb_A[n].c_k (k=0..4);  PB[n] = emb_B[n].c_5
__global__ void k_scan2(const float* __restrict__ embA, const float* __restrict__ embB,
                        const float* __restrict__ cvec, float* __restrict__ PA,
                        float* __restrict__ PB, int blocksA) {
    __shared__ float sc[5 * D];
    const int tid = threadIdx.x;
    const int l = tid & 31;
    const int grp = tid >> 5;

    if ((int)blockIdx.x < blocksA) {
        for (int j = tid; j < 5 * D; j += blockDim.x) sc[j] = cvec[j];  // c0..c4
        __syncthreads();
        const int gStride = blocksA * 8;
        for (int n = blockIdx.x * 8 + grp; n < N_A; n += gStride) {
            const float4 r = *reinterpret_cast<const float4*>(embA + (size_t)n * D + 4 * l);
            float p0 = r.x*sc[0*D+4*l] + r.y*sc[0*D+4*l+1] + r.z*sc[0*D+4*l+2] + r.w*sc[0*D+4*l+3];
            float p1 = r.x*sc[1*D+4*l] + r.y*sc[1*D+4*l+1] + r.z*sc[1*D+4*l+2] + r.w*sc[1*D+4*l+3];
            float p2 = r.x*sc[2*D+4*l] + r.y*sc[2*D+4*l+1] + r.z*sc[2*D+4*l+2] + r.w*sc[2*D+4*l+3];
            float p3 = r.x*sc[3*D+4*l] + r.y*sc[3*D+4*l+1] + r.z*sc[3*D+4*l+2] + r.w*sc[3*D+4*l+3];
            float p4 = r.x*sc[4*D+4*l] + r.y*sc[4*D+4*l+1] + r.z*sc[4*D+4*l+2] + r.w*sc[4*D+4*l+3];
#pragma unroll
            for (int m = 1; m <= 16; m <<= 1) {
                p0 += __shfl_xor(p0, m);
                p1 += __shfl_xor(p1, m);
                p2 += __shfl_xor(p2, m);
                p3 += __shfl_xor(p3, m);
                p4 += __shfl_xor(p4, m);
            }
            if (l == 0) {
                float* o = PA + (size_t)n * 5;
                o[0] = p0; o[1] = p1; o[2] = p2; o[3] = p3; o[4] = p4;
            }
        }
    } else {
        for (int j = tid; j < D; j += blockDim.x) sc[j] = cvec[5 * D + j];  // c5
        __syncthreads();
        const int bBlocks = gridDim.x - blocksA;
        const int gStride = bBlocks * 8;
        for (int n = (blockIdx.x - blocksA) * 8 + grp; n < N_B; n += gStride) {
            const float4 r = *reinterpret_cast<const float4*>(embB + (size_t)n * D + 4 * l);
            float p = r.x*sc[4*l] + r.y*sc[4*l+1] + r.z*sc[4*l+2] + r.w*sc[4*l+3];
#pragma unroll
            for (int m = 1; m <= 16; m <<= 1) p += __shfl_xor(p, m);
            if (l == 0) PB[n] = p;
        }
    }
}

__global__ void k_scatter(const int* __restrict__ ei0, const int* __restrict__ ei1,
                          const int* __restrict__ nh0, const int* __restrict__ nh1,
                          const int* __restrict__ nt0, const int* __restrict__ nt1,
                          const float* __restrict__ PA, const float* __restrict__ PB,
                          float* __restrict__ out) {
    const int total = 2 * E_EDGES + 4 * ES;  // 3.3M
    for (int t = blockIdx.x * blockDim.x + threadIdx.x; t < total;
         t += gridDim.x * blockDim.x) {
        float v;
        if (t < E_EDGES) {
            v = PA[(size_t)ei0[t] * 5 + 0];                               // pos0
        } else if (t < 2 * E_EDGES) {
            v = PA[(size_t)ei1[t - E_EDGES] * 5 + 1];                     // pos1
        } else if (t < 2 * E_EDGES + ES) {
            v = PA[(size_t)nh0[t - 2 * E_EDGES] * 5 + 2];                 // nh0
        } else if (t < 2 * E_EDGES + 2 * ES) {
            v = PA[(size_t)nh1[t - 2 * E_EDGES - ES] * 5 + 3];            // nh1
        } else if (t < 2 * E_EDGES + 3 * ES) {
            const int i = t - 2 * E_EDGES - 2 * ES;
            v = PA[(size_t)nt0[(i >> 4) << 4] * 5 + 4];                   // nt0 (repeat S)
        } else {
            const int i = t - 2 * E_EDGES - 3 * ES;
            v = PB[nt1[(i >> 4) << 4]];                                   // nt1 (repeat S)
        }
        out[t] = v;
    }
}

extern "C" void kernel_launch(void* const* d_in, const int* in_sizes, int n_in,
                              void* d_out, int out_size, void* d_ws, size_t ws_size,
                              hipStream_t stream) {
    const float* embA = (const float*)d_in[0];
    const float* embB = (const float*)d_in[1];
    const float* rel  = (const float*)d_in[2];
    const int* ei0 = (const int*)d_in[3];
    const int* ei1 = (const int*)d_in[4];
    const int* nh0 = (const int*)d_in[5];
    const int* nh1 = (const int*)d_in[6];
    const int* nt0 = (const int*)d_in[7];
    const int* nt1 = (const int*)d_in[8];
    float* out = (float*)d_out;

    int* cntA = (int*)d_ws;
    int* cntB = cntA + 4 * N_A;
    float* svec = (float*)(cntB + 2 * N_B);
    float* cvec = svec + 6 * D;
    float* PA = cvec + 6 * D;
    float* PB = PA + (size_t)N_A * 5;

    // zero counters + svec accumulators (ws is poisoned before every launch)
    const size_t zeroBytes = (size_t)(4 * N_A + 2 * N_B) * sizeof(int) + 6 * D * sizeof(float);
    hipMemsetAsync(d_ws, 0, zeroBytes, stream);

    k_count<<<2048, 256, 0, stream>>>(ei0, ei1, nh0, nh1, nt0, nt1, cntA, cntB);
    k_scan1<<<384 + 192, 256, 0, stream>>>(embA, embB, cntA, cntB, svec, 384);
    k_matvec<<<6, 128, 0, stream>>>(rel, svec, cvec);
    k_scan2<<<512 + 256, 256, 0, stream>>>(embA, embB, cvec, PA, PB, 512);
    k_scatter<<<4096, 256, 0, stream>>>(ei0, ei1, nh0, nh1, nt0, nt1, PA, PB, out);
}

// Round 2
// 247.162 us; speedup vs baseline: 1.0925x; 1.0925x over previous
//
#include <hip/hip_runtime.h>
#include <stdint.h>

#define D 128
#define E_EDGES 50000
#define S_NEG 16
#define N_A 100000
#define N_B 50000
#define ES (E_EDGES * S_NEG)

// ---------------------------------------------------------------------------
// Plan:
//   k_hist    : LDS-privatized byte histograms (no global atomics)
//   k_reduce  : sum byte partials -> int counters cntA[4][N_A], cntB[2][N_B]
//   k_scan1   : one pass over emb tables -> per-block partial weighted sums
//   k_matvec  : reduce partial sums -> s_j ; c_j = scale_j * K_{j%2} @ s_j
//   k_scan2   : one pass over emb tables -> PA[n][5], PB[n] dot-product tables
//   k_scatter : out[i] = P[idx[i]]  (coalesced index reads, L2-resident P)
//
// ws layout (all 4-byte types):
//   u32 partA[44 * 25000]   A-plane byte-hists: A0 c0..3, A1 c4..7, A2 c8..11, A3 c12..43
//   u32 partB[36 * 12500]   B-plane byte-hists: B0 c0..3, B1 c4..35
//   int cntA[4 * N_A]       planes: 0=pos0, 1=nh0, 2=nh1, 3=nt0
//   int cntB[2 * N_B]       planes: 0=pos1, 1=nt1
//   f32 psumA[384 * 512]    scan1 A-block partials [plane0..3][128]
//   f32 psumB[192 * 256]    scan1 B-block partials [plane0..1][128]
//   f32 cvec[6 * D]
//   f32 PA[N_A * 5]
//   f32 PB[N_B]
// ---------------------------------------------------------------------------

__global__ void k_hist(const int* __restrict__ ei0, const int* __restrict__ ei1,
                       const int* __restrict__ nh0, const int* __restrict__ nh1,
                       const int* __restrict__ nt0, const int* __restrict__ nt1,
                       uint32_t* __restrict__ partA, uint32_t* __restrict__ partB) {
    __shared__ uint32_t h[12500];  // 50k bins as packed bytes
    const int tid = threadIdx.x;
    for (int w = tid; w < 12500; w += 256) h[w] = 0;
    __syncthreads();

    const int b = blockIdx.x;
    const int* src;
    long long base;
    int n_items, stride, lo;
    uint32_t* dst;
    if (b < 8) {                       // A0: pos0 tails = ei0[E..2E)
        const int c = b >> 1, half = b & 1;
        src = ei0; base = E_EDGES + (long long)c * 12500; n_items = 12500; stride = 1;
        lo = half * 50000; dst = partA + (size_t)c * 25000 + half * 12500;
    } else if (b < 16) {               // A1: nh0 column 0
        const int c = (b - 8) >> 1, half = (b - 8) & 1;
        src = nh0; base = (long long)c * 12500 * S_NEG; n_items = 12500; stride = S_NEG;
        lo = half * 50000; dst = partA + (size_t)(4 + c) * 25000 + half * 12500;
    } else if (b < 24) {               // A2: nh1 column 0
        const int c = (b - 16) >> 1, half = (b - 16) & 1;
        src = nh1; base = (long long)c * 12500 * S_NEG; n_items = 12500; stride = S_NEG;
        lo = half * 50000; dst = partA + (size_t)(8 + c) * 25000 + half * 12500;
    } else if (b < 88) {               // A3: nt0 flat (800k, 32 chunks)
        const int c = (b - 24) >> 1, half = (b - 24) & 1;
        src = nt0; base = (long long)c * 25000; n_items = 25000; stride = 1;
        lo = half * 50000; dst = partA + (size_t)(12 + c) * 25000 + half * 12500;
    } else if (b < 92) {               // B0: pos1 tails = ei1[E..2E)
        const int c = b - 88;
        src = ei1; base = E_EDGES + (long long)c * 12500; n_items = 12500; stride = 1;
        lo = 0; dst = partB + (size_t)c * 12500;
    } else {                           // B1: nt1 flat (800k, 32 chunks)
        const int c = b - 92;
        src = nt1; base = (long long)c * 25000; n_items = 25000; stride = 1;
        lo = 0; dst = partB + (size_t)(4 + c) * 12500;
    }

    for (int i = tid; i < n_items; i += 256) {
        const int idx = src[base + (long long)i * stride];
        const unsigned r = (unsigned)(idx - lo);
        if (r < 50000u) atomicAdd(&h[r >> 2], 1u << ((r & 3u) * 8u));
    }
    __syncthreads();
    for (int w = tid; w < 12500; w += 256) dst[w] = h[w];
}

__global__ void k_reduce(const uint32_t* __restrict__ partA,
                         const uint32_t* __restrict__ partB,
                         int* __restrict__ cntA, int* __restrict__ cntB) {
    const int t = blockIdx.x * 256 + threadIdx.x;
    if (t >= 125000) return;
    if (t < 100000) {
        const int p = t / 25000, w = t - p * 25000;
        const int start = (p < 3) ? p * 4 : 12;
        const int cnt = (p < 3) ? 4 : 32;
        unsigned s0 = 0, s1 = 0, s2 = 0, s3 = 0;
        const uint32_t* bp = partA + (size_t)start * 25000 + w;
        for (int c = 0; c < cnt; ++c) {
            const unsigned v = bp[(size_t)c * 25000];
            s0 += v & 255u; s1 += (v >> 8) & 255u; s2 += (v >> 16) & 255u; s3 += v >> 24;
        }
        int* o = cntA + (size_t)p * N_A + 4 * w;
        o[0] = (int)s0; o[1] = (int)s1; o[2] = (int)s2; o[3] = (int)s3;
    } else {
        const int t2 = t - 100000;
        const int p = t2 / 12500, w = t2 - p * 12500;
        const int start = p ? 4 : 0;
        const int cnt = p ? 32 : 4;
        unsigned s0 = 0, s1 = 0, s2 = 0, s3 = 0;
        const uint32_t* bp = partB + (size_t)start * 12500 + w;
        for (int c = 0; c < cnt; ++c) {
            const unsigned v = bp[(size_t)c * 12500];
            s0 += v & 255u; s1 += (v >> 8) & 255u; s2 += (v >> 16) & 255u; s3 += v >> 24;
        }
        int* o = cntB + (size_t)p * N_B + 4 * w;
        o[0] = (int)s0; o[1] = (int)s1; o[2] = (int)s2; o[3] = (int)s3;
    }
}

// Weighted table scan: per-block partial s_j written dense (no global atomics).
__global__ void k_scan1(const float* __restrict__ embA, const float* __restrict__ embB,
                        const int* __restrict__ cntA, const int* __restrict__ cntB,
                        float* __restrict__ psumA, float* __restrict__ psumB, int blocksA) {
    __shared__ float sds[4 * D];
    const int tid = threadIdx.x;
    const int l = tid & 31;
    const int grp = tid >> 5;  // 0..7

    for (int j = tid; j < 4 * D; j += blockDim.x) sds[j] = 0.f;
    __syncthreads();

    if ((int)blockIdx.x < blocksA) {
        const int gStride = blocksA * 8;
        float a0=0,a1=0,a2=0,a3=0, b0=0,b1=0,b2=0,b3=0;
        float c0=0,c1=0,c2=0,c3=0, d0=0,d1=0,d2=0,d3=0;
        for (int n = blockIdx.x * 8 + grp; n < N_A; n += gStride) {
            const int w0 = cntA[n], w1 = cntA[N_A + n];
            const int w2 = cntA[2 * N_A + n], w3 = cntA[3 * N_A + n];
            if ((w0 | w1 | w2 | w3) == 0) continue;
            const float4 r = *reinterpret_cast<const float4*>(embA + (size_t)n * D + 4 * l);
            float f;
            f = (float)w0; a0 += f*r.x; a1 += f*r.y; a2 += f*r.z; a3 += f*r.w;
            f = (float)w1; b0 += f*r.x; b1 += f*r.y; b2 += f*r.z; b3 += f*r.w;
            f = (float)w2; c0 += f*r.x; c1 += f*r.y; c2 += f*r.z; c3 += f*r.w;
            f = (float)w3; d0 += f*r.x; d1 += f*r.y; d2 += f*r.z; d3 += f*r.w;
        }
        atomicAdd(&sds[0*D + 4*l+0], a0); atomicAdd(&sds[0*D + 4*l+1], a1);
        atomicAdd(&sds[0*D + 4*l+2], a2); atomicAdd(&sds[0*D + 4*l+3], a3);
        atomicAdd(&sds[1*D + 4*l+0], b0); atomicAdd(&sds[1*D + 4*l+1], b1);
        atomicAdd(&sds[1*D + 4*l+2], b2); atomicAdd(&sds[1*D + 4*l+3], b3);
        atomicAdd(&sds[2*D + 4*l+0], c0); atomicAdd(&sds[2*D + 4*l+1], c1);
        atomicAdd(&sds[2*D + 4*l+2], c2); atomicAdd(&sds[2*D + 4*l+3], c3);
        atomicAdd(&sds[3*D + 4*l+0], d0); atomicAdd(&sds[3*D + 4*l+1], d1);
        atomicAdd(&sds[3*D + 4*l+2], d2); atomicAdd(&sds[3*D + 4*l+3], d3);
        __syncthreads();
        for (int j = tid; j < 4 * D; j += blockDim.x)
            psumA[(size_t)blockIdx.x * 512 + j] = sds[j];
    } else {
        const int bi = blockIdx.x - blocksA;
        const int bBlocks = gridDim.x - blocksA;
        const int gStride = bBlocks * 8;
        float a0=0,a1=0,a2=0,a3=0, b0=0,b1=0,b2=0,b3=0;
        for (int n = bi * 8 + grp; n < N_B; n += gStride) {
            const int w0 = cntB[n], w1 = cntB[N_B + n];
            if ((w0 | w1) == 0) continue;
            const float4 r = *reinterpret_cast<const float4*>(embB + (size_t)n * D + 4 * l);
            float f;
            f = (float)w0; a0 += f*r.x; a1 += f*r.y; a2 += f*r.z; a3 += f*r.w;
            f = (float)w1; b0 += f*r.x; b1 += f*r.y; b2 += f*r.z; b3 += f*r.w;
        }
        atomicAdd(&sds[0*D + 4*l+0], a0); atomicAdd(&sds[0*D + 4*l+1], a1);
        atomicAdd(&sds[0*D + 4*l+2], a2); atomicAdd(&sds[0*D + 4*l+3], a3);
        atomicAdd(&sds[1*D + 4*l+0], b0); atomicAdd(&sds[1*D + 4*l+1], b1);
        atomicAdd(&sds[1*D + 4*l+2], b2); atomicAdd(&sds[1*D + 4*l+3], b3);
        __syncthreads();
        for (int j = tid; j < 2 * D; j += blockDim.x)
            psumB[(size_t)bi * 256 + j] = sds[j];
    }
}

// Reduce scan1 partials -> s_j; then c_j[i] = scale_j * sum_k K_{j%2}[i,k]*s_j[k].
__global__ void k_matvec(const float* __restrict__ rel,
                         const float* __restrict__ psumA, const float* __restrict__ psumB,
                         float* __restrict__ cvec) {
    const int j = blockIdx.x;  // 0..5: pos0,pos1,nh0,nh1,nt0,nt1
    const int i = threadIdx.x; // 0..127
    __shared__ float sv[D];
    float s = 0.f;
    if (j == 1 || j == 5) {
        const int plane = (j == 1) ? 0 : 1;
        for (int b = 0; b < 192; ++b) s += psumB[(size_t)b * 256 + plane * D + i];
    } else {
        const int plane = (j == 0) ? 0 : (j - 1);  // 0,1,2,3 for jobs 0,2,3,4
        for (int b = 0; b < 384; ++b) s += psumA[(size_t)b * 512 + plane * D + i];
    }
    sv[i] = s;
    __syncthreads();

    const float* Kp = rel + (size_t)(j & 1) * D * D;
    const float scale = (j == 2 || j == 3) ? (float)S_NEG : 1.0f;
    float acc = 0.f;
#pragma unroll 8
    for (int k = 0; k < D; ++k) acc += Kp[(size_t)i * D + k] * sv[k];
    cvec[j * D + i] = acc * scale;
}

// PA[n*5+k] = emb_A[n].c_k (k=0..4);  PB[n] = emb_B[n].c_5
__global__ void k_scan2(const float* __restrict__ embA, const float* __restrict__ embB,
                        const float* __restrict__ cvec, float* __restrict__ PA,
                        float* __restrict__ PB, int blocksA) {
    __shared__ float sc[5 * D];
    const int tid = threadIdx.x;
    const int l = tid & 31;
    const int grp = tid >> 5;

    if ((int)blockIdx.x < blocksA) {
        for (int j = tid; j < 5 * D; j += blockDim.x) sc[j] = cvec[j];  // c0..c4
        __syncthreads();
        const int gStride = blocksA * 8;
        for (int n = blockIdx.x * 8 + grp; n < N_A; n += gStride) {
            const float4 r = *reinterpret_cast<const float4*>(embA + (size_t)n * D + 4 * l);
            float p0 = r.x*sc[0*D+4*l] + r.y*sc[0*D+4*l+1] + r.z*sc[0*D+4*l+2] + r.w*sc[0*D+4*l+3];
            float p1 = r.x*sc[1*D+4*l] + r.y*sc[1*D+4*l+1] + r.z*sc[1*D+4*l+2] + r.w*sc[1*D+4*l+3];
            float p2 = r.x*sc[2*D+4*l] + r.y*sc[2*D+4*l+1] + r.z*sc[2*D+4*l+2] + r.w*sc[2*D+4*l+3];
            float p3 = r.x*sc[3*D+4*l] + r.y*sc[3*D+4*l+1] + r.z*sc[3*D+4*l+2] + r.w*sc[3*D+4*l+3];
            float p4 = r.x*sc[4*D+4*l] + r.y*sc[4*D+4*l+1] + r.z*sc[4*D+4*l+2] + r.w*sc[4*D+4*l+3];
#pragma unroll
            for (int m = 1; m <= 16; m <<= 1) {
                p0 += __shfl_xor(p0, m);
                p1 += __shfl_xor(p1, m);
                p2 += __shfl_xor(p2, m);
                p3 += __shfl_xor(p3, m);
                p4 += __shfl_xor(p4, m);
            }
            if (l == 0) {
                float* o = PA + (size_t)n * 5;
                o[0] = p0; o[1] = p1; o[2] = p2; o[3] = p3; o[4] = p4;
            }
        }
    } else {
        for (int j = tid; j < D; j += blockDim.x) sc[j] = cvec[5 * D + j];  // c5
        __syncthreads();
        const int bBlocks = gridDim.x - blocksA;
        const int gStride = bBlocks * 8;
        for (int n = (blockIdx.x - blocksA) * 8 + grp; n < N_B; n += gStride) {
            const float4 r = *reinterpret_cast<const float4*>(embB + (size_t)n * D + 4 * l);
            float p = r.x*sc[4*l] + r.y*sc[4*l+1] + r.z*sc[4*l+2] + r.w*sc[4*l+3];
#pragma unroll
            for (int m = 1; m <= 16; m <<= 1) p += __shfl_xor(p, m);
            if (l == 0) PB[n] = p;
        }
    }
}

__global__ void k_scatter(const int* __restrict__ ei0, const int* __restrict__ ei1,
                          const int* __restrict__ nh0, const int* __restrict__ nh1,
                          const int* __restrict__ nt0, const int* __restrict__ nt1,
                          const float* __restrict__ PA, const float* __restrict__ PB,
                          float* __restrict__ out) {
    const int total = 2 * E_EDGES + 4 * ES;  // 3.3M
    for (int t = blockIdx.x * blockDim.x + threadIdx.x; t < total;
         t += gridDim.x * blockDim.x) {
        float v;
        if (t < E_EDGES) {
            v = PA[(size_t)ei0[t] * 5 + 0];                               // pos0
        } else if (t < 2 * E_EDGES) {
            v = PA[(size_t)ei1[t - E_EDGES] * 5 + 1];                     // pos1
        } else if (t < 2 * E_EDGES + ES) {
            v = PA[(size_t)nh0[t - 2 * E_EDGES] * 5 + 2];                 // nh0
        } else if (t < 2 * E_EDGES + 2 * ES) {
            v = PA[(size_t)nh1[t - 2 * E_EDGES - ES] * 5 + 3];            // nh1
        } else if (t < 2 * E_EDGES + 3 * ES) {
            const int i = t - 2 * E_EDGES - 2 * ES;
            v = PA[(size_t)nt0[(i >> 4) << 4] * 5 + 4];                   // nt0 (repeat S)
        } else {
            const int i = t - 2 * E_EDGES - 3 * ES;
            v = PB[nt1[(i >> 4) << 4]];                                   // nt1 (repeat S)
        }
        out[t] = v;
    }
}

extern "C" void kernel_launch(void* const* d_in, const int* in_sizes, int n_in,
                              void* d_out, int out_size, void* d_ws, size_t ws_size,
                              hipStream_t stream) {
    const float* embA = (const float*)d_in[0];
    const float* embB = (const float*)d_in[1];
    const float* rel  = (const float*)d_in[2];
    const int* ei0 = (const int*)d_in[3];
    const int* ei1 = (const int*)d_in[4];
    const int* nh0 = (const int*)d_in[5];
    const int* nh1 = (const int*)d_in[6];
    const int* nt0 = (const int*)d_in[7];
    const int* nt1 = (const int*)d_in[8];
    float* out = (float*)d_out;

    uint32_t* partA = (uint32_t*)d_ws;                    // 44*25000
    uint32_t* partB = partA + (size_t)44 * 25000;         // 36*12500
    int* cntA = (int*)(partB + (size_t)36 * 12500);       // 4*N_A
    int* cntB = cntA + 4 * N_A;                           // 2*N_B
    float* psumA = (float*)(cntB + 2 * N_B);              // 384*512
    float* psumB = psumA + (size_t)384 * 512;             // 192*256
    float* cvec  = psumB + (size_t)192 * 256;             // 6*D
    float* PA    = cvec + 6 * D;                          // N_A*5
    float* PB    = PA + (size_t)N_A * 5;                  // N_B

    // Every ws word used is fully written before read -> no memset needed.
    k_hist<<<124, 256, 0, stream>>>(ei0, ei1, nh0, nh1, nt0, nt1, partA, partB);
    k_reduce<<<(125000 + 255) / 256, 256, 0, stream>>>(partA, partB, cntA, cntB);
    k_scan1<<<384 + 192, 256, 0, stream>>>(embA, embB, cntA, cntB, psumA, psumB, 384);
    k_matvec<<<6, 128, 0, stream>>>(rel, psumA, psumB, cvec);
    k_scan2<<<512 + 256, 256, 0, stream>>>(embA, embB, cvec, PA, PB, 512);
    k_scatter<<<4096, 256, 0, stream>>>(ei0, ei1, nh0, nh1, nt0, nt1, PA, PB, out);
}